// Round 4
// baseline (262.852 us; speedup 1.0000x reference)
//
#include <hip/hip_runtime.h>
#include <hip/hip_bf16.h>
#include <math.h>

#define NEGF (-1e30f)

// ws float offsets
#define P_OFF   0u           // spanmax partials: 192*8*768 = 1179648
#define ENT_OFF 1179648u     // ent (B,3,D) = 147456
#define EA_OFF  1327104u     // e state A
#define EB_OFF  1474560u     // e state B
#define SP_OFF  1622016u     // s-partials [16][192][5] = 15360
#define PP_OFF  1637376u     // pred partials 8*64*512 = 262144

__device__ __forceinline__ float sigmoidf_(float x){ return 1.0f/(1.0f+expf(-x)); }

// ---- span max: partials over 64-row chunks ----
__global__ __launch_bounds__(192) void k_spanmax_partial(
    const float* __restrict__ enc, const int* __restrict__ ent_pos, float* __restrict__ ws)
{
    int bi = blockIdx.y; int c = blockIdx.x; int t = threadIdx.x;
    int b = bi/3;
    int st = ent_pos[bi*2+0], en = ent_pos[bi*2+1];
    int r0 = max(st, c*64), r1 = min(en, c*64+63);
    float4 m = make_float4(NEGF,NEGF,NEGF,NEGF);
    const float4* e4 = (const float4*)enc + (size_t)b*512*192 + t;
    int r = r0;
    for (; r+3<=r1; r+=4){
        float4 v0 = e4[(size_t)(r  )*192];
        float4 v1 = e4[(size_t)(r+1)*192];
        float4 v2 = e4[(size_t)(r+2)*192];
        float4 v3 = e4[(size_t)(r+3)*192];
        m.x=fmaxf(m.x,fmaxf(fmaxf(v0.x,v1.x),fmaxf(v2.x,v3.x)));
        m.y=fmaxf(m.y,fmaxf(fmaxf(v0.y,v1.y),fmaxf(v2.y,v3.y)));
        m.z=fmaxf(m.z,fmaxf(fmaxf(v0.z,v1.z),fmaxf(v2.z,v3.z)));
        m.w=fmaxf(m.w,fmaxf(fmaxf(v0.w,v1.w),fmaxf(v2.w,v3.w)));
    }
    for (; r<=r1; ++r){
        float4 v = e4[(size_t)r*192];
        m.x=fmaxf(m.x,v.x); m.y=fmaxf(m.y,v.y); m.z=fmaxf(m.z,v.z); m.w=fmaxf(m.w,v.w);
    }
    ((float4*)(ws+P_OFF))[(bi*8+c)*192 + t] = m;
}

// ---- reduce partials -> ent, init e-state, ent_score output ----
__global__ __launch_bounds__(256) void k_spanmax_reduce(
    const float* __restrict__ projW, const float* __restrict__ projb,
    float* __restrict__ ws, float* __restrict__ out)
{
    __shared__ float red[256];
    int bi = blockIdx.x; int t = threadIdx.x;
    float local = 0.f;
    if (t < 192){
        float4 m = make_float4(NEGF,NEGF,NEGF,NEGF);
        const float4* p4 = (const float4*)(ws+P_OFF);
        for (int c=0;c<8;++c){
            float4 v = p4[(bi*8+c)*192+t];
            m.x=fmaxf(m.x,v.x); m.y=fmaxf(m.y,v.y); m.z=fmaxf(m.z,v.z); m.w=fmaxf(m.w,v.w);
        }
        ((float4*)(ws+ENT_OFF))[bi*192+t] = m;
        ((float4*)(ws+EA_OFF))[bi*192+t] = m;
        float4 w = ((const float4*)projW)[t];
        local = m.x*w.x + m.y*w.y + m.z*w.z + m.w*w.w;
    }
    red[t]=local; __syncthreads();
    for (int off=128; off>0; off>>=1){ if (t<off) red[t]+=red[t+off]; __syncthreads(); }
    if (t==0) out[320 + bi] = sigmoidf_(red[0] + projb[0]);
}

// ---- pred head: split-K partials (64 x 512, K=2304 in 8 chunks) ----
__global__ __launch_bounds__(256) void k_pred_part(
    const float* __restrict__ predW1, float* __restrict__ ws)
{
    int ct = blockIdx.x, rb = blockIdx.y, ks = blockIdx.z;
    int tx = threadIdx.x & 31, ty = threadIdx.x >> 5;
    int row = rb*8+ty, col = ct*32+tx;
    const float* A = ws + ENT_OFF + (size_t)row*2304 + ks*288;
    const float* W = predW1 + (size_t)(ks*288)*512 + col;
    float acc = 0.f;
    #pragma unroll 4
    for (int k=0;k<288;++k){ acc = fmaf(A[k], W[(size_t)k*512], acc); }
    ws[PP_OFF + ((size_t)(ks*64+row))*512 + col] = acc;
}

// ---- pred finish: reduce + relu + (512->5) head -> rel ----
__global__ __launch_bounds__(256) void k_pred_fin(
    const float* __restrict__ pb1, const float* __restrict__ predW2,
    const float* __restrict__ pb2, float* __restrict__ ws, float* __restrict__ out)
{
    __shared__ float ph[512];
    __shared__ float red[256];
    int b = blockIdx.x, t = threadIdx.x;
    for (int c = t; c < 512; c += 256){
        float s = 0.f;
        for (int ks=0;ks<8;++ks) s += ws[PP_OFF + ((size_t)(ks*64+b))*512 + c];
        ph[c] = fmaxf(s + pb1[c], 0.f);
    }
    __syncthreads();
    for (int c=0;c<5;++c){
        float local = ph[t]*predW2[t*5+c] + ph[t+256]*predW2[(t+256)*5+c];
        red[t]=local; __syncthreads();
        for (int off=128; off>0; off>>=1){ if (t<off) red[t]+=red[t+off]; __syncthreads(); }
        if (t==0) out[b*5+c] = red[0] + pb2[c];
        __syncthreads();
    }
}

// ---- vr fused v2: 512 thr, full-K, shared-product trick, K in 32 chunks of 48 ----
// grid (16 ct, 32 bg). Block: 2 b's (6 rows), 32 hidden cols.
__global__ __launch_bounds__(512) void k_vr_fused(
    const float* __restrict__ W1, const float* __restrict__ b1,
    const float* __restrict__ W2, const float* __restrict__ eSrc,
    float* __restrict__ ws)
{
    __shared__ float eL[4608];    // [2 b][3 p][768]
    __shared__ float red[4096];   // [kq32][tp16][8]
    int ct = blockIdx.x, bg = blockIdx.y;
    int t = threadIdx.x;
    int b0 = bg*2;
    const float* eBase = eSrc + (size_t)b0*2304;
    for (int idx=t; idx<4608; idx+=512) eL[idx] = eBase[idx];
    __syncthreads();

    int tp = t & 15;
    int kq = t >> 4;             // 0..31, K-chunk of 48
    int c0 = ct*32;
    int col = c0 + 2*tp;
    const float* Wp = W1 + (size_t)(kq*48)*512 + col;
    // half1 (k<768): P = e idx1, Q = e idx0; half2: P = e idx2, Q = e idx1
    int off1 = (kq<16) ? (768 + kq*48) : (1536 + (kq-16)*48);
    int off2 = (kq<16) ? (      kq*48) : (768  + (kq-16)*48);
    const float* pP0 = eL + off1;
    const float* pQ0 = eL + off2;
    const float* pP1 = eL + 2304 + off1;
    const float* pQ1 = eL + 2304 + off2;
    float aP0x=0,aP0y=0,aQ0x=0,aQ0y=0,aP1x=0,aP1y=0,aQ1x=0,aQ1y=0;
    float2 w = *(const float2*)(Wp);
    #pragma unroll 4
    for (int i=0;i<48;++i){
        float2 wn = (i<47) ? *(const float2*)(Wp + (size_t)(i+1)*512) : w;
        float p0 = pP0[i], q0 = pQ0[i], p1 = pP1[i], q1 = pQ1[i];
        aP0x = fmaf(p0,w.x,aP0x); aP0y = fmaf(p0,w.y,aP0y);
        aQ0x = fmaf(q0,w.x,aQ0x); aQ0y = fmaf(q0,w.y,aQ0y);
        aP1x = fmaf(p1,w.x,aP1x); aP1y = fmaf(p1,w.y,aP1y);
        aQ1x = fmaf(q1,w.x,aQ1x); aQ1y = fmaf(q1,w.y,aQ1y);
        w = wn;
    }
    float* rp = red + (kq*16 + tp)*8;
    rp[0]=aP0x; rp[1]=aP0y; rp[2]=aQ0x; rp[3]=aQ0y;
    rp[4]=aP1x; rp[5]=aP1y; rp[6]=aQ1x; rp[7]=aQ1y;
    __syncthreads();

    if (t < 64){
        int tc = t & 31, bb = t >> 5;
        int jb = bb*4 + (tc & 1);
        int rtp = tc >> 1;
        float SP1=0,SP2=0,SQ1=0,SQ2=0;
        #pragma unroll
        for (int k=0;k<16;++k){
            SP1 += red[(k*16+rtp)*8 + jb];
            SQ1 += red[(k*16+rtp)*8 + jb + 2];
            SP2 += red[((k+16)*16+rtp)*8 + jb];
            SQ2 += red[((k+16)*16+rtp)*8 + jb + 2];
        }
        int c = c0 + tc;
        float bv = b1[c];
        float h0 = fmaxf(SP1+SP2+bv, 0.f);
        float h1 = fmaxf(SQ1+SP2+bv, 0.f);
        float h2 = fmaxf(SQ1+SQ2+bv, 0.f);
        float w20 = W2[c*5+0], w21 = W2[c*5+1], w22 = W2[c*5+2], w23 = W2[c*5+3], w24 = W2[c*5+4];
        float pr[15] = { h0*w20,h0*w21,h0*w22,h0*w23,h0*w24,
                         h1*w20,h1*w21,h1*w22,h1*w23,h1*w24,
                         h2*w20,h2*w21,h2*w22,h2*w23,h2*w24 };
        #pragma unroll
        for (int j=0;j<15;++j){
            float v = pr[j];
            v += __shfl_down(v, 16, 32);
            v += __shfl_down(v, 8, 32);
            v += __shfl_down(v, 4, 32);
            v += __shfl_down(v, 2, 32);
            v += __shfl_down(v, 1, 32);
            pr[j] = v;
        }
        if (tc == 0){
            float* sp = ws + SP_OFF + ((size_t)ct*192 + (size_t)(b0+bb)*3)*5;
            #pragma unroll
            for (int j=0;j<15;++j) sp[j] = pr[j];
        }
    }
}

// ---- gate fused: finish s, build u, full-K gate GEMM, sigmoid + combine -> e' ----
// grid (24 ct, 32 bg), 256 thr. Block: 2 b's (6 rows), 32 out cols, K=1536.
__global__ __launch_bounds__(256) void k_gate_fused(
    const float* __restrict__ gW, const float* __restrict__ gb,
    const float* __restrict__ ArW, const float* __restrict__ Arb,
    const float* __restrict__ Vb2,
    const float* __restrict__ eSrc, float* __restrict__ eDst,
    float* __restrict__ ws, float* __restrict__ finalOut)
{
    __shared__ float eL[4608];
    __shared__ float uL[4608];
    __shared__ float red[3072];   // [16][16][12]
    __shared__ float sL[32];      // [bb][p][cc]
    int ct = blockIdx.x, bg = blockIdx.y;
    int t = threadIdx.x;
    int b0 = bg*2;
    const float* eBase = eSrc + (size_t)b0*2304;
    for (int idx=t; idx<4608; idx+=256) eL[idx] = eBase[idx];
    if (t < 30){
        int bb = t/15, pc = t%15, cc = pc%5;
        int row = (b0+bb)*3 + pc/5;
        float pre = Vb2[cc];
        #pragma unroll
        for (int q=0;q<16;++q) pre += ws[SP_OFF + ((size_t)q*192 + row)*5 + cc];
        sL[t] = sigmoidf_(pre);
    }
    __syncthreads();
    // build u = (s@Ar + Arb) * e
    for (int idx=t; idx<4608; idx+=256){
        int r = idx / 768;
        int k = idx - r*768;
        int bb = r / 3;  int p = r - bb*3;
        const float* s = sL + bb*15 + p*5;
        float a = Arb[k] + s[0]*ArW[k] + s[1]*ArW[768+k] + s[2]*ArW[1536+k]
                         + s[3]*ArW[2304+k] + s[4]*ArW[3072+k];
        uL[idx] = a * eL[idx];
    }
    __syncthreads();

    int tp = t & 15, kq = t >> 4;
    int c0 = ct*32;
    int col = c0 + 2*tp;
    const float* Wp = gW + (size_t)(kq*96)*768 + col;
    const float* A = (kq<8) ? uL : eL;
    int kb = (kq & 7)*96;
    float acc[6][2];
    #pragma unroll
    for (int r=0;r<6;++r){ acc[r][0]=0.f; acc[r][1]=0.f; }
    float2 w = *(const float2*)(Wp);
    #pragma unroll 4
    for (int i=0;i<96;++i){
        float2 wn = (i<95) ? *(const float2*)(Wp + (size_t)(i+1)*768) : w;
        #pragma unroll
        for (int r=0;r<6;++r){
            float a = A[r*768 + kb + i];
            acc[r][0] = fmaf(a, w.x, acc[r][0]);
            acc[r][1] = fmaf(a, w.y, acc[r][1]);
        }
        w = wn;
    }
    float* rp = red + (kq*16+tp)*12;
    #pragma unroll
    for (int r=0;r<6;++r){ rp[r*2]=acc[r][0]; rp[r*2+1]=acc[r][1]; }
    __syncthreads();

    for (int o=t; o<192; o+=256){
        int tc = o & 31, rr = o >> 5;
        int bb = rr/3, p = rr - bb*3;
        int j = rr*2 + (tc&1);
        int rtp = tc >> 1;
        float gp = 0.f;
        #pragma unroll
        for (int k=0;k<16;++k) gp += red[(k*16+rtp)*12 + j];
        int jc = c0 + tc;
        float g = sigmoidf_(gp + gb[jc]);
        float e = eL[bb*2304 + p*768 + jc];
        float u = uL[bb*2304 + p*768 + jc];
        float val = g*e + (1.f-g)*u;
        size_t oi = ((size_t)(b0+bb)*3 + p)*768 + jc;
        eDst[oi] = val;
        if (finalOut) finalOut[oi] = val;
    }
}

extern "C" void kernel_launch(void* const* d_in, const int* in_sizes, int n_in,
                              void* d_out, int out_size, void* d_ws, size_t ws_size,
                              hipStream_t stream)
{
    const float* enc     = (const float*)d_in[0];
    const int*   ent_pos = (const int*)d_in[1];
    const float* ArW     = (const float*)d_in[2];
    const float* Arb     = (const float*)d_in[3];
    const float* VrW1    = (const float*)d_in[4];
    const float* Vrb1    = (const float*)d_in[5];
    const float* VrW2    = (const float*)d_in[6];
    const float* Vrb2    = (const float*)d_in[7];
    const float* gateW   = (const float*)d_in[8];
    const float* gateb   = (const float*)d_in[9];
    const float* predW1  = (const float*)d_in[10];
    const float* predb1  = (const float*)d_in[11];
    const float* predW2  = (const float*)d_in[12];
    const float* predb2  = (const float*)d_in[13];
    const float* projW   = (const float*)d_in[14];
    const float* projb   = (const float*)d_in[15];
    float* out = (float*)d_out;
    float* ws  = (float*)d_ws;

    hipLaunchKernelGGL(k_spanmax_partial, dim3(8,192), dim3(192), 0, stream, enc, ent_pos, ws);
    hipLaunchKernelGGL(k_spanmax_reduce, dim3(192), dim3(256), 0, stream, projW, projb, ws, out);
    hipLaunchKernelGGL(k_pred_part, dim3(16,8,8), dim3(256), 0, stream, predW1, ws);
    hipLaunchKernelGGL(k_pred_fin, dim3(64), dim3(256), 0, stream, predb1, predW2, predb2, ws, out);
    for (int it=0; it<5; ++it){
        float* eS = ws + ((it&1)==0 ? EA_OFF : EB_OFF);
        float* eD = ws + ((it&1)==0 ? EB_OFF : EA_OFF);
        hipLaunchKernelGGL(k_vr_fused,   dim3(16,32), dim3(512), 0, stream, VrW1, Vrb1, VrW2, eS, ws);
        hipLaunchKernelGGL(k_gate_fused, dim3(24,32), dim3(256), 0, stream, gateW, gateb, ArW, Arb, Vrb2,
                           eS, eD, ws, (it==4) ? (out+512) : (float*)nullptr);
    }
}

// Round 5
// 173.497 us; speedup vs baseline: 1.5150x; 1.5150x over previous
//
#include <hip/hip_runtime.h>
#include <hip/hip_bf16.h>
#include <math.h>

#define NEGF (-1e30f)

// ws float offsets
#define P_OFF   0u           // spanmax partials: 192*8*768 = 1179648
#define ENT_OFF 1179648u     // ent (B,3,D) = 147456
#define EA_OFF  1327104u     // e state A
#define EB_OFF  1474560u     // e state B
#define SP_OFF  1622016u     // s-partials [16][192][5] = 15360
#define PP_OFF  1637376u     // pred partials 8*64*512 = 262144

__device__ __forceinline__ float sigmoidf_(float x){ return 1.0f/(1.0f+expf(-x)); }

// ---- span max: partials over 64-row chunks (4x unrolled row loop) ----
__global__ __launch_bounds__(192) void k_spanmax_partial(
    const float* __restrict__ enc, const int* __restrict__ ent_pos, float* __restrict__ ws)
{
    int bi = blockIdx.y; int c = blockIdx.x; int t = threadIdx.x;
    int b = bi/3;
    int st = ent_pos[bi*2+0], en = ent_pos[bi*2+1];
    int r0 = max(st, c*64), r1 = min(en, c*64+63);
    float4 m = make_float4(NEGF,NEGF,NEGF,NEGF);
    const float4* e4 = (const float4*)enc + (size_t)b*512*192 + t;
    int r = r0;
    for (; r+3<=r1; r+=4){
        float4 v0 = e4[(size_t)(r  )*192];
        float4 v1 = e4[(size_t)(r+1)*192];
        float4 v2 = e4[(size_t)(r+2)*192];
        float4 v3 = e4[(size_t)(r+3)*192];
        m.x=fmaxf(m.x,fmaxf(fmaxf(v0.x,v1.x),fmaxf(v2.x,v3.x)));
        m.y=fmaxf(m.y,fmaxf(fmaxf(v0.y,v1.y),fmaxf(v2.y,v3.y)));
        m.z=fmaxf(m.z,fmaxf(fmaxf(v0.z,v1.z),fmaxf(v2.z,v3.z)));
        m.w=fmaxf(m.w,fmaxf(fmaxf(v0.w,v1.w),fmaxf(v2.w,v3.w)));
    }
    for (; r<=r1; ++r){
        float4 v = e4[(size_t)r*192];
        m.x=fmaxf(m.x,v.x); m.y=fmaxf(m.y,v.y); m.z=fmaxf(m.z,v.z); m.w=fmaxf(m.w,v.w);
    }
    ((float4*)(ws+P_OFF))[(bi*8+c)*192 + t] = m;
}

// ---- reduce partials -> ent, init e-state, ent_score output ----
__global__ __launch_bounds__(256) void k_spanmax_reduce(
    const float* __restrict__ projW, const float* __restrict__ projb,
    float* __restrict__ ws, float* __restrict__ out)
{
    __shared__ float red[256];
    int bi = blockIdx.x; int t = threadIdx.x;
    float local = 0.f;
    if (t < 192){
        float4 m = make_float4(NEGF,NEGF,NEGF,NEGF);
        const float4* p4 = (const float4*)(ws+P_OFF);
        for (int c=0;c<8;++c){
            float4 v = p4[(bi*8+c)*192+t];
            m.x=fmaxf(m.x,v.x); m.y=fmaxf(m.y,v.y); m.z=fmaxf(m.z,v.z); m.w=fmaxf(m.w,v.w);
        }
        ((float4*)(ws+ENT_OFF))[bi*192+t] = m;
        ((float4*)(ws+EA_OFF))[bi*192+t] = m;
        float4 w = ((const float4*)projW)[t];
        local = m.x*w.x + m.y*w.y + m.z*w.z + m.w*w.w;
    }
    red[t]=local; __syncthreads();
    for (int off=128; off>0; off>>=1){ if (t<off) red[t]+=red[t+off]; __syncthreads(); }
    if (t==0) out[320 + bi] = sigmoidf_(red[0] + projb[0]);
}

// ---- pred head: split-K partials (64 x 512, K=2304 in 8 chunks) ----
__global__ __launch_bounds__(256) void k_pred_part(
    const float* __restrict__ predW1, float* __restrict__ ws)
{
    int ct = blockIdx.x, rb = blockIdx.y, ks = blockIdx.z;
    int tx = threadIdx.x & 31, ty = threadIdx.x >> 5;
    int row = rb*8+ty, col = ct*32+tx;
    const float* A = ws + ENT_OFF + (size_t)row*2304 + ks*288;
    const float* W = predW1 + (size_t)(ks*288)*512 + col;
    float acc = 0.f;
    #pragma unroll 4
    for (int k=0;k<288;++k){ acc = fmaf(A[k], W[(size_t)k*512], acc); }
    ws[PP_OFF + ((size_t)(ks*64+row))*512 + col] = acc;
}

// ---- pred finish: reduce + relu + (512->5) head -> rel ----
__global__ __launch_bounds__(256) void k_pred_fin(
    const float* __restrict__ pb1, const float* __restrict__ predW2,
    const float* __restrict__ pb2, float* __restrict__ ws, float* __restrict__ out)
{
    __shared__ float ph[512];
    __shared__ float red[256];
    int b = blockIdx.x, t = threadIdx.x;
    for (int c = t; c < 512; c += 256){
        float s = 0.f;
        for (int ks=0;ks<8;++ks) s += ws[PP_OFF + ((size_t)(ks*64+b))*512 + c];
        ph[c] = fmaxf(s + pb1[c], 0.f);
    }
    __syncthreads();
    for (int c=0;c<5;++c){
        float local = ph[t]*predW2[t*5+c] + ph[t+256]*predW2[(t+256)*5+c];
        red[t]=local; __syncthreads();
        for (int off=128; off>0; off>>=1){ if (t<off) red[t]+=red[t+off]; __syncthreads(); }
        if (t==0) out[b*5+c] = red[0] + pb2[c];
        __syncthreads();
    }
}

// ---- vr fused: full-K GEMM (shared-product trick) + relu + 512->5 head partials ----
// grid (16 ct, 32 bg), 256 thr. Block: 2 b's (6 rows), 32 hidden cols, K=1536.
__global__ __launch_bounds__(256) void k_vr_fused(
    const float* __restrict__ W1, const float* __restrict__ b1,
    const float* __restrict__ W2, const float* __restrict__ eSrc,
    float* __restrict__ ws)
{
    __shared__ float eL[4608];    // [2 b][3 p][768]
    __shared__ float red[2048];   // [kq16][tp16][8]
    int ct = blockIdx.x, bg = blockIdx.y;
    int t = threadIdx.x;
    int b0 = bg*2;
    const float* eBase = eSrc + (size_t)b0*2304;
    for (int idx=t; idx<4608; idx+=256) eL[idx] = eBase[idx];
    __syncthreads();

    int tp = t & 15;
    int kq = t >> 4;             // 0..15, K-chunk of 96
    int c0 = ct*32;
    int col = c0 + 2*tp;
    const float* Wp = W1 + (size_t)(kq*96)*512 + col;
    // half1 (k<768): P=e2 (row0), Q=e1 (rows1,2); half2: P=e3 (rows0,1), Q=e2 (row2)
    int off1 = (kq<8) ? (768 + kq*96) : (1536 + (kq-8)*96);
    int off2 = (kq<8) ? (      kq*96) : (768  + (kq-8)*96);
    const float* pP0 = eL + off1;
    const float* pQ0 = eL + off2;
    const float* pP1 = eL + 2304 + off1;
    const float* pQ1 = eL + 2304 + off2;
    float aP0x=0,aP0y=0,aQ0x=0,aQ0y=0,aP1x=0,aP1y=0,aQ1x=0,aQ1y=0;
    #pragma unroll 8
    for (int i=0;i<96;++i){
        float2 w = *(const float2*)(Wp + (size_t)i*512);
        float p0 = pP0[i], q0 = pQ0[i], p1 = pP1[i], q1 = pQ1[i];
        aP0x = fmaf(p0,w.x,aP0x); aP0y = fmaf(p0,w.y,aP0y);
        aQ0x = fmaf(q0,w.x,aQ0x); aQ0y = fmaf(q0,w.y,aQ0y);
        aP1x = fmaf(p1,w.x,aP1x); aP1y = fmaf(p1,w.y,aP1y);
        aQ1x = fmaf(q1,w.x,aQ1x); aQ1y = fmaf(q1,w.y,aQ1y);
    }
    float* rp = red + (kq*16 + tp)*8;
    rp[0]=aP0x; rp[1]=aP0y; rp[2]=aQ0x; rp[3]=aQ0y;
    rp[4]=aP1x; rp[5]=aP1y; rp[6]=aQ1x; rp[7]=aQ1y;
    __syncthreads();

    if (t < 64){
        int tc = t & 31, bb = t >> 5;
        int jb = bb*4 + (tc & 1);
        int rtp = tc >> 1;
        float SP1=0,SP2=0,SQ1=0,SQ2=0;
        #pragma unroll
        for (int k=0;k<8;++k){
            SP1 += red[(k*16+rtp)*8 + jb];
            SQ1 += red[(k*16+rtp)*8 + jb + 2];
            SP2 += red[((k+8)*16+rtp)*8 + jb];
            SQ2 += red[((k+8)*16+rtp)*8 + jb + 2];
        }
        int c = c0 + tc;
        float bv = b1[c];
        float h0 = fmaxf(SP1+SP2+bv, 0.f);
        float h1 = fmaxf(SQ1+SP2+bv, 0.f);
        float h2 = fmaxf(SQ1+SQ2+bv, 0.f);
        float w20 = W2[c*5+0], w21 = W2[c*5+1], w22 = W2[c*5+2], w23 = W2[c*5+3], w24 = W2[c*5+4];
        float pr[15] = { h0*w20,h0*w21,h0*w22,h0*w23,h0*w24,
                         h1*w20,h1*w21,h1*w22,h1*w23,h1*w24,
                         h2*w20,h2*w21,h2*w22,h2*w23,h2*w24 };
        #pragma unroll
        for (int j=0;j<15;++j){
            float v = pr[j];
            v += __shfl_down(v, 16, 32);
            v += __shfl_down(v, 8, 32);
            v += __shfl_down(v, 4, 32);
            v += __shfl_down(v, 2, 32);
            v += __shfl_down(v, 1, 32);
            pr[j] = v;
        }
        if (tc == 0){
            float* sp = ws + SP_OFF + ((size_t)ct*192 + (size_t)(b0+bb)*3)*5;
            #pragma unroll
            for (int j=0;j<15;++j) sp[j] = pr[j];
        }
    }
}

// ---- gate fused: finish s, build u, full-K gate GEMM, sigmoid + combine -> e' ----
// grid (24 ct, 32 bg), 256 thr. Block: 2 b's (6 rows), 32 out cols, K=1536.
__global__ __launch_bounds__(256) void k_gate_fused(
    const float* __restrict__ gW, const float* __restrict__ gb,
    const float* __restrict__ ArW, const float* __restrict__ Arb,
    const float* __restrict__ Vb2,
    const float* __restrict__ eSrc, float* __restrict__ eDst,
    float* __restrict__ ws, float* __restrict__ finalOut)
{
    __shared__ float eL[4608];
    __shared__ float uL[4608];
    __shared__ float red[3072];   // [16][16][12]
    __shared__ float sL[32];      // [bb][p][cc]
    int ct = blockIdx.x, bg = blockIdx.y;
    int t = threadIdx.x;
    int b0 = bg*2;
    const float* eBase = eSrc + (size_t)b0*2304;
    for (int idx=t; idx<4608; idx+=256) eL[idx] = eBase[idx];
    if (t < 30){
        int bb = t/15, pc = t%15, cc = pc%5;
        int row = (b0+bb)*3 + pc/5;
        float pre = Vb2[cc];
        #pragma unroll
        for (int q=0;q<16;++q) pre += ws[SP_OFF + ((size_t)q*192 + row)*5 + cc];
        sL[t] = sigmoidf_(pre);
    }
    __syncthreads();
    // build u = (s@Ar + Arb) * e
    for (int idx=t; idx<4608; idx+=256){
        int r = idx / 768;
        int k = idx - r*768;
        int bb = r / 3;  int p = r - bb*3;
        const float* s = sL + bb*15 + p*5;
        float a = Arb[k] + s[0]*ArW[k] + s[1]*ArW[768+k] + s[2]*ArW[1536+k]
                         + s[3]*ArW[2304+k] + s[4]*ArW[3072+k];
        uL[idx] = a * eL[idx];
    }
    __syncthreads();

    int tp = t & 15, kq = t >> 4;
    int c0 = ct*32;
    int col = c0 + 2*tp;
    const float* Wp = gW + (size_t)(kq*96)*768 + col;
    const float* A = (kq<8) ? uL : eL;
    int kb = (kq & 7)*96;
    float acc[6][2];
    #pragma unroll
    for (int r=0;r<6;++r){ acc[r][0]=0.f; acc[r][1]=0.f; }
    #pragma unroll 4
    for (int i=0;i<96;++i){
        float2 w = *(const float2*)(Wp + (size_t)i*768);
        #pragma unroll
        for (int r=0;r<6;++r){
            float a = A[r*768 + kb + i];
            acc[r][0] = fmaf(a, w.x, acc[r][0]);
            acc[r][1] = fmaf(a, w.y, acc[r][1]);
        }
    }
    float* rp = red + (kq*16+tp)*12;
    #pragma unroll
    for (int r=0;r<6;++r){ rp[r*2]=acc[r][0]; rp[r*2+1]=acc[r][1]; }
    __syncthreads();

    for (int o=t; o<192; o+=256){
        int tc = o & 31, rr = o >> 5;
        int bb = rr/3, p = rr - bb*3;
        int j = rr*2 + (tc&1);
        int rtp = tc >> 1;
        float gp = 0.f;
        #pragma unroll
        for (int k=0;k<16;++k) gp += red[(k*16+rtp)*12 + j];
        int jc = c0 + tc;
        float g = sigmoidf_(gp + gb[jc]);
        float e = eL[bb*2304 + p*768 + jc];
        float u = uL[bb*2304 + p*768 + jc];
        float val = g*e + (1.f-g)*u;
        size_t oi = ((size_t)(b0+bb)*3 + p)*768 + jc;
        eDst[oi] = val;
        if (finalOut) finalOut[oi] = val;
    }
}

extern "C" void kernel_launch(void* const* d_in, const int* in_sizes, int n_in,
                              void* d_out, int out_size, void* d_ws, size_t ws_size,
                              hipStream_t stream)
{
    const float* enc     = (const float*)d_in[0];
    const int*   ent_pos = (const int*)d_in[1];
    const float* ArW     = (const float*)d_in[2];
    const float* Arb     = (const float*)d_in[3];
    const float* VrW1    = (const float*)d_in[4];
    const float* Vrb1    = (const float*)d_in[5];
    const float* VrW2    = (const float*)d_in[6];
    const float* Vrb2    = (const float*)d_in[7];
    const float* gateW   = (const float*)d_in[8];
    const float* gateb   = (const float*)d_in[9];
    const float* predW1  = (const float*)d_in[10];
    const float* predb1  = (const float*)d_in[11];
    const float* predW2  = (const float*)d_in[12];
    const float* predb2  = (const float*)d_in[13];
    const float* projW   = (const float*)d_in[14];
    const float* projb   = (const float*)d_in[15];
    float* out = (float*)d_out;
    float* ws  = (float*)d_ws;

    hipLaunchKernelGGL(k_spanmax_partial, dim3(8,192), dim3(192), 0, stream, enc, ent_pos, ws);
    hipLaunchKernelGGL(k_spanmax_reduce, dim3(192), dim3(256), 0, stream, projW, projb, ws, out);
    hipLaunchKernelGGL(k_pred_part, dim3(16,8,8), dim3(256), 0, stream, predW1, ws);
    hipLaunchKernelGGL(k_pred_fin, dim3(64), dim3(256), 0, stream, predb1, predW2, predb2, ws, out);
    for (int it=0; it<5; ++it){
        float* eS = ws + ((it&1)==0 ? EA_OFF : EB_OFF);
        float* eD = ws + ((it&1)==0 ? EB_OFF : EA_OFF);
        hipLaunchKernelGGL(k_vr_fused,   dim3(16,32), dim3(256), 0, stream, VrW1, Vrb1, VrW2, eS, ws);
        hipLaunchKernelGGL(k_gate_fused, dim3(24,32), dim3(256), 0, stream, gateW, gateb, ArW, Arb, Vrb2,
                           eS, eD, ws, (it==4) ? (out+512) : (float*)nullptr);
    }
}

// Round 6
// 164.982 us; speedup vs baseline: 1.5932x; 1.0516x over previous
//
#include <hip/hip_runtime.h>
#include <hip/hip_bf16.h>
#include <math.h>

#define NEGF (-1e30f)

// ws float offsets
#define P_OFF   0u           // spanmax partials: 192*8*768 = 1179648
#define ENT_OFF 1179648u     // ent (B,3,D) = 147456
#define EA_OFF  1327104u     // e state A
#define EB_OFF  1474560u     // e state B
#define SP_OFF  1622016u     // s-partials [8][192][5] = 7680
#define PP_OFF  1637376u     // pred partials 8*64*512 = 262144

__device__ __forceinline__ float sigmoidf_(float x){ return 1.0f/(1.0f+expf(-x)); }

// ---- span max: partials over 64-row chunks (4x unrolled row loop) ----
__global__ __launch_bounds__(192) void k_spanmax_partial(
    const float* __restrict__ enc, const int* __restrict__ ent_pos, float* __restrict__ ws)
{
    int bi = blockIdx.y; int c = blockIdx.x; int t = threadIdx.x;
    int b = bi/3;
    int st = ent_pos[bi*2+0], en = ent_pos[bi*2+1];
    int r0 = max(st, c*64), r1 = min(en, c*64+63);
    float4 m = make_float4(NEGF,NEGF,NEGF,NEGF);
    const float4* e4 = (const float4*)enc + (size_t)b*512*192 + t;
    int r = r0;
    for (; r+3<=r1; r+=4){
        float4 v0 = e4[(size_t)(r  )*192];
        float4 v1 = e4[(size_t)(r+1)*192];
        float4 v2 = e4[(size_t)(r+2)*192];
        float4 v3 = e4[(size_t)(r+3)*192];
        m.x=fmaxf(m.x,fmaxf(fmaxf(v0.x,v1.x),fmaxf(v2.x,v3.x)));
        m.y=fmaxf(m.y,fmaxf(fmaxf(v0.y,v1.y),fmaxf(v2.y,v3.y)));
        m.z=fmaxf(m.z,fmaxf(fmaxf(v0.z,v1.z),fmaxf(v2.z,v3.z)));
        m.w=fmaxf(m.w,fmaxf(fmaxf(v0.w,v1.w),fmaxf(v2.w,v3.w)));
    }
    for (; r<=r1; ++r){
        float4 v = e4[(size_t)r*192];
        m.x=fmaxf(m.x,v.x); m.y=fmaxf(m.y,v.y); m.z=fmaxf(m.z,v.z); m.w=fmaxf(m.w,v.w);
    }
    ((float4*)(ws+P_OFF))[(bi*8+c)*192 + t] = m;
}

// ---- reduce partials -> ent, init e-state, ent_score output ----
__global__ __launch_bounds__(256) void k_spanmax_reduce(
    const float* __restrict__ projW, const float* __restrict__ projb,
    float* __restrict__ ws, float* __restrict__ out)
{
    __shared__ float red[256];
    int bi = blockIdx.x; int t = threadIdx.x;
    float local = 0.f;
    if (t < 192){
        float4 m = make_float4(NEGF,NEGF,NEGF,NEGF);
        const float4* p4 = (const float4*)(ws+P_OFF);
        for (int c=0;c<8;++c){
            float4 v = p4[(bi*8+c)*192+t];
            m.x=fmaxf(m.x,v.x); m.y=fmaxf(m.y,v.y); m.z=fmaxf(m.z,v.z); m.w=fmaxf(m.w,v.w);
        }
        ((float4*)(ws+ENT_OFF))[bi*192+t] = m;
        ((float4*)(ws+EA_OFF))[bi*192+t] = m;
        float4 w = ((const float4*)projW)[t];
        local = m.x*w.x + m.y*w.y + m.z*w.z + m.w*w.w;
    }
    red[t]=local; __syncthreads();
    for (int off=128; off>0; off>>=1){ if (t<off) red[t]+=red[t+off]; __syncthreads(); }
    if (t==0) out[320 + bi] = sigmoidf_(red[0] + projb[0]);
}

// ---- pred head: split-K partials (64 x 512, K=2304 in 8 chunks) ----
__global__ __launch_bounds__(256) void k_pred_part(
    const float* __restrict__ predW1, float* __restrict__ ws)
{
    int ct = blockIdx.x, rb = blockIdx.y, ks = blockIdx.z;
    int tx = threadIdx.x & 31, ty = threadIdx.x >> 5;
    int row = rb*8+ty, col = ct*32+tx;
    const float* A = ws + ENT_OFF + (size_t)row*2304 + ks*288;
    const float* W = predW1 + (size_t)(ks*288)*512 + col;
    float acc = 0.f;
    #pragma unroll 4
    for (int k=0;k<288;++k){ acc = fmaf(A[k], W[(size_t)k*512], acc); }
    ws[PP_OFF + ((size_t)(ks*64+row))*512 + col] = acc;
}

// ---- pred finish: reduce + relu + (512->5) head -> rel ----
__global__ __launch_bounds__(256) void k_pred_fin(
    const float* __restrict__ pb1, const float* __restrict__ predW2,
    const float* __restrict__ pb2, float* __restrict__ ws, float* __restrict__ out)
{
    __shared__ float ph[512];
    __shared__ float red[256];
    int b = blockIdx.x, t = threadIdx.x;
    for (int c = t; c < 512; c += 256){
        float s = 0.f;
        for (int ks=0;ks<8;++ks) s += ws[PP_OFF + ((size_t)(ks*64+b))*512 + c];
        ph[c] = fmaxf(s + pb1[c], 0.f);
    }
    __syncthreads();
    for (int c=0;c<5;++c){
        float local = ph[t]*predW2[t*5+c] + ph[t+256]*predW2[(t+256)*5+c];
        red[t]=local; __syncthreads();
        for (int off=128; off>0; off>>=1){ if (t<off) red[t]+=red[t+off]; __syncthreads(); }
        if (t==0) out[b*5+c] = red[0] + pb2[c];
        __syncthreads();
    }
}

// ---- vr fused v3: 4 cols/thread, full-K, shared-product trick ----
// grid (8 ct, 32 bg), 256 thr. Block: 2 b's (6 rows), 64 hidden cols, K=1536.
__global__ __launch_bounds__(256) void k_vr_fused(
    const float* __restrict__ W1, const float* __restrict__ b1,
    const float* __restrict__ W2, const float* __restrict__ eSrc,
    float* __restrict__ ws)
{
    __shared__ float eL[4608];      // [2 b][3 p][768]
    __shared__ float red[16*16*17]; // [kq16][tp16][16+pad]
    int ct = blockIdx.x, bg = blockIdx.y;
    int t = threadIdx.x;
    int b0 = bg*2;
    const float* eBase = eSrc + (size_t)b0*2304;
    for (int idx=t; idx<4608; idx+=256) eL[idx] = eBase[idx];
    __syncthreads();

    int tp = t & 15;
    int kq = t >> 4;             // 0..15, K-chunk of 96
    int c0 = ct*64;
    int col = c0 + 4*tp;
    const float* Wp = W1 + (size_t)(kq*96)*512 + col;
    // half1 (k<768): P=e2 (row0), Q=e1 (rows1,2); half2: P=e3 (rows0,1), Q=e2 (row2)
    int off1 = (kq<8) ? (768 + kq*96) : (1536 + (kq-8)*96);
    int off2 = (kq<8) ? (      kq*96) : (768  + (kq-8)*96);
    const float* pP0 = eL + off1;
    const float* pQ0 = eL + off2;
    const float* pP1 = eL + 2304 + off1;
    const float* pQ1 = eL + 2304 + off2;
    float aP0[4]={0,0,0,0}, aQ0[4]={0,0,0,0}, aP1[4]={0,0,0,0}, aQ1[4]={0,0,0,0};
    #pragma unroll 8
    for (int i=0;i<96;++i){
        float4 w = *(const float4*)(Wp + (size_t)i*512);
        float p0 = pP0[i], q0 = pQ0[i], p1 = pP1[i], q1 = pQ1[i];
        aP0[0]=fmaf(p0,w.x,aP0[0]); aP0[1]=fmaf(p0,w.y,aP0[1]); aP0[2]=fmaf(p0,w.z,aP0[2]); aP0[3]=fmaf(p0,w.w,aP0[3]);
        aQ0[0]=fmaf(q0,w.x,aQ0[0]); aQ0[1]=fmaf(q0,w.y,aQ0[1]); aQ0[2]=fmaf(q0,w.z,aQ0[2]); aQ0[3]=fmaf(q0,w.w,aQ0[3]);
        aP1[0]=fmaf(p1,w.x,aP1[0]); aP1[1]=fmaf(p1,w.y,aP1[1]); aP1[2]=fmaf(p1,w.z,aP1[2]); aP1[3]=fmaf(p1,w.w,aP1[3]);
        aQ1[0]=fmaf(q1,w.x,aQ1[0]); aQ1[1]=fmaf(q1,w.y,aQ1[1]); aQ1[2]=fmaf(q1,w.z,aQ1[2]); aQ1[3]=fmaf(q1,w.w,aQ1[3]);
    }
    float* rp = red + (kq*16 + tp)*17;
    #pragma unroll
    for (int c=0;c<4;++c){ rp[c]=aP0[c]; rp[4+c]=aQ0[c]; rp[8+c]=aP1[c]; rp[12+c]=aQ1[c]; }
    __syncthreads();

    if (t < 128){
        int bb = t >> 6;          // wave 0 -> b0, wave 1 -> b0+1
        int tc = t & 63;          // col within 64
        int tp2 = tc >> 2, c = tc & 3;
        int base = bb*8;
        float SP1=0,SP2=0,SQ1=0,SQ2=0;
        #pragma unroll
        for (int k=0;k<8;++k){
            SP1 += red[(k*16+tp2)*17 + base + c];
            SQ1 += red[(k*16+tp2)*17 + base + 4 + c];
            SP2 += red[((k+8)*16+tp2)*17 + base + c];
            SQ2 += red[((k+8)*16+tp2)*17 + base + 4 + c];
        }
        int cc = c0 + tc;
        float bv = b1[cc];
        float h0 = fmaxf(SP1+SP2+bv, 0.f);
        float h1 = fmaxf(SQ1+SP2+bv, 0.f);
        float h2 = fmaxf(SQ1+SQ2+bv, 0.f);
        float w20 = W2[cc*5+0], w21 = W2[cc*5+1], w22 = W2[cc*5+2], w23 = W2[cc*5+3], w24 = W2[cc*5+4];
        float pr[15] = { h0*w20,h0*w21,h0*w22,h0*w23,h0*w24,
                         h1*w20,h1*w21,h1*w22,h1*w23,h1*w24,
                         h2*w20,h2*w21,h2*w22,h2*w23,h2*w24 };
        #pragma unroll
        for (int j=0;j<15;++j){
            float v = pr[j];
            v += __shfl_down(v, 32);
            v += __shfl_down(v, 16);
            v += __shfl_down(v, 8);
            v += __shfl_down(v, 4);
            v += __shfl_down(v, 2);
            v += __shfl_down(v, 1);
            pr[j] = v;
        }
        if (tc == 0){
            float* sp = ws + SP_OFF + ((size_t)ct*192 + (size_t)(b0+bb)*3)*5;
            #pragma unroll
            for (int j=0;j<15;++j) sp[j] = pr[j];
        }
    }
}

// ---- gate fused v3: 4 cols/thread; finish s, build u, full-K GEMM, combine ----
// grid (12 ct, 32 bg), 256 thr. Block: 2 b's (6 rows), 64 out cols, K=1536.
__global__ __launch_bounds__(256) void k_gate_fused(
    const float* __restrict__ gW, const float* __restrict__ gb,
    const float* __restrict__ ArW, const float* __restrict__ Arb,
    const float* __restrict__ Vb2,
    const float* __restrict__ eSrc, float* __restrict__ eDst,
    float* __restrict__ ws, float* __restrict__ finalOut)
{
    __shared__ float eL[4608];
    __shared__ float uL[4608];
    __shared__ float red[16*16*25];  // [kq16][tp16][24+pad]
    __shared__ float sL[32];         // [bb][p][cc]
    int ct = blockIdx.x, bg = blockIdx.y;
    int t = threadIdx.x;
    int b0 = bg*2;
    const float* eBase = eSrc + (size_t)b0*2304;
    for (int idx=t; idx<4608; idx+=256) eL[idx] = eBase[idx];
    if (t < 30){
        int bb = t/15, pc = t%15, cc = pc%5;
        int row = (b0+bb)*3 + pc/5;
        float pre = Vb2[cc];
        #pragma unroll
        for (int q=0;q<8;++q) pre += ws[SP_OFF + ((size_t)q*192 + row)*5 + cc];
        sL[t] = sigmoidf_(pre);
    }
    __syncthreads();
    // build u = (s@Ar + Arb) * e
    for (int idx=t; idx<4608; idx+=256){
        int r = idx / 768;
        int k = idx - r*768;
        int bb = r / 3;  int p = r - bb*3;
        const float* s = sL + bb*15 + p*5;
        float a = Arb[k] + s[0]*ArW[k] + s[1]*ArW[768+k] + s[2]*ArW[1536+k]
                         + s[3]*ArW[2304+k] + s[4]*ArW[3072+k];
        uL[idx] = a * eL[idx];
    }
    __syncthreads();

    int tp = t & 15, kq = t >> 4;
    int c0 = ct*64;
    int col = c0 + 4*tp;
    const float* Wp = gW + (size_t)(kq*96)*768 + col;
    const float* A = (kq<8) ? uL : eL;
    int kb = (kq & 7)*96;
    float acc[6][4];
    #pragma unroll
    for (int r=0;r<6;++r){ acc[r][0]=0.f; acc[r][1]=0.f; acc[r][2]=0.f; acc[r][3]=0.f; }
    #pragma unroll 4
    for (int i=0;i<96;++i){
        float4 w = *(const float4*)(Wp + (size_t)i*768);
        #pragma unroll
        for (int r=0;r<6;++r){
            float a = A[r*768 + kb + i];
            acc[r][0] = fmaf(a, w.x, acc[r][0]);
            acc[r][1] = fmaf(a, w.y, acc[r][1]);
            acc[r][2] = fmaf(a, w.z, acc[r][2]);
            acc[r][3] = fmaf(a, w.w, acc[r][3]);
        }
    }
    float* rp = red + (kq*16+tp)*25;
    #pragma unroll
    for (int r=0;r<6;++r){
        rp[r*4+0]=acc[r][0]; rp[r*4+1]=acc[r][1]; rp[r*4+2]=acc[r][2]; rp[r*4+3]=acc[r][3];
    }
    __syncthreads();

    for (int o=t; o<384; o+=256){
        int tc = o & 63, rr = o >> 6;      // col within 64, row 0..5
        int tp2 = tc >> 2, c = tc & 3;
        int bb = rr/3, p = rr - bb*3;
        float gp = 0.f;
        #pragma unroll
        for (int k=0;k<16;++k) gp += red[(k*16+tp2)*25 + rr*4 + c];
        int jc = c0 + tc;
        float g = sigmoidf_(gp + gb[jc]);
        float e = eL[bb*2304 + p*768 + jc];
        float u = uL[bb*2304 + p*768 + jc];
        float val = g*e + (1.f-g)*u;
        size_t oi = ((size_t)(b0+bb)*3 + p)*768 + jc;
        eDst[oi] = val;
        if (finalOut) finalOut[oi] = val;
    }
}

extern "C" void kernel_launch(void* const* d_in, const int* in_sizes, int n_in,
                              void* d_out, int out_size, void* d_ws, size_t ws_size,
                              hipStream_t stream)
{
    const float* enc     = (const float*)d_in[0];
    const int*   ent_pos = (const int*)d_in[1];
    const float* ArW     = (const float*)d_in[2];
    const float* Arb     = (const float*)d_in[3];
    const float* VrW1    = (const float*)d_in[4];
    const float* Vrb1    = (const float*)d_in[5];
    const float* VrW2    = (const float*)d_in[6];
    const float* Vrb2    = (const float*)d_in[7];
    const float* gateW   = (const float*)d_in[8];
    const float* gateb   = (const float*)d_in[9];
    const float* predW1  = (const float*)d_in[10];
    const float* predb1  = (const float*)d_in[11];
    const float* predW2  = (const float*)d_in[12];
    const float* predb2  = (const float*)d_in[13];
    const float* projW   = (const float*)d_in[14];
    const float* projb   = (const float*)d_in[15];
    float* out = (float*)d_out;
    float* ws  = (float*)d_ws;

    hipLaunchKernelGGL(k_spanmax_partial, dim3(8,192), dim3(192), 0, stream, enc, ent_pos, ws);
    hipLaunchKernelGGL(k_spanmax_reduce, dim3(192), dim3(256), 0, stream, projW, projb, ws, out);
    hipLaunchKernelGGL(k_pred_part, dim3(16,8,8), dim3(256), 0, stream, predW1, ws);
    hipLaunchKernelGGL(k_pred_fin, dim3(64), dim3(256), 0, stream, predb1, predW2, predb2, ws, out);
    for (int it=0; it<5; ++it){
        float* eS = ws + ((it&1)==0 ? EA_OFF : EB_OFF);
        float* eD = ws + ((it&1)==0 ? EB_OFF : EA_OFF);
        hipLaunchKernelGGL(k_vr_fused,   dim3(8,32),  dim3(256), 0, stream, VrW1, Vrb1, VrW2, eS, ws);
        hipLaunchKernelGGL(k_gate_fused, dim3(12,32), dim3(256), 0, stream, gateW, gateb, ArW, Arb, Vrb2,
                           eS, eD, ws, (it==4) ? (out+512) : (float*)nullptr);
    }
}